// Round 6
// baseline (276.600 us; speedup 1.0000x reference)
//
#include <hip/hip_runtime.h>
#include <hip/hip_bf16.h>
#include <math.h>

#define BB 1024     // batch
#define LL 50       // sequence length
#define DD 256      // embedding dim
#define TWO_D 512
#define NN 40000    // nodes
#define DEG 12      // neighbors per node (adj_rows = repeat(arange(N), DEG))
#define NITER 50    // entmax bisect iterations

typedef __attribute__((ext_vector_type(8))) short short8;
typedef __attribute__((ext_vector_type(4))) float floatx4;

__device__ __forceinline__ float wave_sum64(float v) {
#pragma unroll
    for (int off = 32; off > 0; off >>= 1) v += __shfl_xor(v, off, 64);
    return v;
}
__device__ __forceinline__ float wave_max64(float v) {
#pragma unroll
    for (int off = 32; off > 0; off >>= 1) v = fmaxf(v, __shfl_xor(v, off, 64));
    return v;
}
__device__ __forceinline__ float bf2f(ushort u) {
    union { unsigned int i; float f; } c; c.i = ((unsigned int)u) << 16; return c.f;
}
__device__ __forceinline__ ushort f2bf(float f) {
    __hip_bfloat16 h = __float2bfloat16(f);
    return *(ushort*)&h;
}
__device__ __forceinline__ float hw_exp2(float x) { return __builtin_amdgcn_exp2f(x); }
__device__ __forceinline__ float hw_log2(float x) { return __builtin_amdgcn_logf(x); }

// K0: ebf = bf16(item_emb)
__global__ __launch_bounds__(256) void k_emb_bf16(
    const float* __restrict__ emb, ushort* __restrict__ ebf)
{
    int i = (blockIdx.x * 256 + threadIdx.x) * 4;
    float4 v = *(const float4*)(emb + i);
    ushort4 o;
    o.x = f2bf(v.x); o.y = f2bf(v.y); o.z = f2bf(v.z); o.w = f2bf(v.w);
    *(ushort4*)(ebf + i) = o;
}

// K1: per-node conv, one wave per node. All 12 neighbor rows loaded as
// independent in-flight loads (MLP), then accumulated.
__global__ __launch_bounds__(256) void k_conv_all_bf16(
    const ushort* __restrict__ ebf, const int* __restrict__ adj_cols,
    const float* __restrict__ adj_vals, ushort* __restrict__ gbf)
{
    int wv = threadIdx.x >> 6, lane = threadIdx.x & 63;
    int n = blockIdx.x * 4 + wv;
    int colv = 0; float valv = 0.f;
    if (lane < DEG) { colv = adj_cols[n * DEG + lane]; valv = adj_vals[n * DEG + lane]; }
    int cols[DEG]; float vals[DEG];
#pragma unroll
    for (int k = 0; k < DEG; ++k) {
        cols[k] = __shfl(colv, k, 64);
        vals[k] = __shfl(valv, k, 64);
    }
    ushort4 s = *(const ushort4*)(ebf + (size_t)n * DD + lane * 4);
    ushort4 e[DEG];
#pragma unroll
    for (int k = 0; k < DEG; ++k)
        e[k] = *(const ushort4*)(ebf + (size_t)cols[k] * DD + lane * 4);
    float a0 = bf2f(s.x), a1 = bf2f(s.y), a2 = bf2f(s.z), a3 = bf2f(s.w);
#pragma unroll
    for (int k = 0; k < DEG; ++k) {
        float v = vals[k];
        a0 += v * bf2f(e[k].x); a1 += v * bf2f(e[k].y);
        a2 += v * bf2f(e[k].z); a3 += v * bf2f(e[k].w);
    }
    ushort4 o;
    o.x = f2bf(0.5f * a0); o.y = f2bf(0.5f * a1);
    o.z = f2bf(0.5f * a2); o.w = f2bf(0.5f * a3);
    *(ushort4*)(gbf + (size_t)n * DD + lane * 4) = o;
}

// Kprep: w1t[n*256+k] = bf16(at_w1[k*256+n])
__global__ __launch_bounds__(256) void k_prep_w1(
    const float* __restrict__ at_w1, ushort* __restrict__ w1t)
{
    __shared__ ushort s[4][DD];
    int k0 = blockIdx.x * 4;
    int n = threadIdx.x;
#pragma unroll
    for (int j = 0; j < 4; ++j) s[j][n] = f2bf(at_w1[(k0 + j) * DD + n]);
    __syncthreads();
    ushort4 pk;
    pk.x = s[0][n]; pk.y = s[1][n]; pk.z = s[2][n]; pk.w = s[3][n];
    *(ushort4*)(w1t + n * DD + k0) = pk;
}

// Kw: combined weights.
//  Wc[k][n] = sum_d wf_w[d][k]*at_w2[d][n]            (512x256)
//  v[k]     = sum_d wf_w[d][k]*aw[d]                  (512)
//  block 0 also: bc[n] = sum_d wf_b[d]*at_w2[d][n] + at_bias[n];  c0 = wf_b.aw + ab
__global__ __launch_bounds__(256) void k_wprep(
    const float* __restrict__ wf_w, const float* __restrict__ wf_b,
    const float* __restrict__ at_w2, const float* __restrict__ at_bias,
    const float* __restrict__ aw, const float* __restrict__ ab,
    float* __restrict__ Wc, float* __restrict__ v,
    float* __restrict__ bc, float* __restrict__ c0)
{
    __shared__ float wred[4];
    int k = blockIdx.x;
    int tid = threadIdx.x;
    int lane = tid & 63, wv = tid >> 6;

    float acc = 0.f;
#pragma unroll 4
    for (int d = 0; d < DD; ++d)
        acc += wf_w[d * TWO_D + k] * at_w2[d * DD + tid];
    Wc[k * DD + tid] = acc;

    // v[k]
    float s1 = wf_w[tid * TWO_D + k] * aw[tid];
    s1 = wave_sum64(s1);
    if (lane == 0) wred[wv] = s1;
    __syncthreads();
    if (tid == 0) v[k] = wred[0] + wred[1] + wred[2] + wred[3];

    if (k == 0) {
        float acc2 = at_bias[tid];
#pragma unroll 4
        for (int d = 0; d < DD; ++d)
            acc2 += wf_b[d] * at_w2[d * DD + tid];
        bc[tid] = acc2;
        __syncthreads();
        float s2 = wf_b[tid] * aw[tid];
        s2 = wave_sum64(s2);
        if (lane == 0) wred[wv] = s2;
        __syncthreads();
        if (tid == 0) c0[0] = wred[0] + wred[1] + wred[2] + wred[3] + ab[0];
    }
}

// Kt: t2[b,n] = tgt[b,:] @ Wc[:,n] + bc[n];  ntile==0 blocks also emit alpha.
// grid = (BB/4) * 4 ntiles = 1024 blocks; block: 4 batch rows x 64 cols.
__global__ __launch_bounds__(256) void k_t2a(
    const float* __restrict__ tgt, const float* __restrict__ Wc,
    const float* __restrict__ bc, const float* __restrict__ v,
    const float* __restrict__ c0, float* __restrict__ t2,
    float* __restrict__ alpha)
{
    __shared__ float x_s[4 * TWO_D];
    int btile = blockIdx.x >> 2, ntile = blockIdx.x & 3;
    int b0 = btile * 4, n0 = ntile * 64;
    int tid = threadIdx.x;
    int j = tid >> 6, lane = tid & 63;
    for (int i = tid; i < 4 * TWO_D; i += 256) x_s[i] = tgt[b0 * TWO_D + i];
    __syncthreads();

    float acc = bc[n0 + lane];
    const float* xr = x_s + j * TWO_D;
#pragma unroll 8
    for (int k = 0; k < TWO_D; ++k)
        acc += xr[k] * Wc[k * DD + n0 + lane];
    t2[(b0 + j) * DD + n0 + lane] = acc;

    if (ntile == 0) {
        float s = 0.f;
#pragma unroll
        for (int i = 0; i < 8; ++i) s += xr[lane + 64 * i] * v[lane + 64 * i];
        s = wave_sum64(s);
        if (lane == 0) {
            float a = 1.f + 1.f / (1.f + expf(-(s + c0[0])));
            if (a == 1.f) a = 1.00001f;
            alpha[b0 + j] = a;
        }
    }
}

// K3 (MFMA): G = gbf @ W1   (node-level; 64 rows x 256 cols per block)
__global__ __launch_bounds__(256) void k_gw1(
    const ushort* __restrict__ gbf, const ushort* __restrict__ w1t,
    ushort* __restrict__ G)
{
    __shared__ __align__(16) ushort sA[64 * 72];
    __shared__ __align__(16) ushort sB[256 * 72];
    int tid = threadIdx.x;
    int blk = blockIdx.x;
    int lane = tid & 63, wv = tid >> 6;
    int cn = lane & 15, q = lane >> 4;
    int n0 = wv * 64;
    const size_t rowbase = (size_t)blk * 64;

    floatx4 acc[4][4];
#pragma unroll
    for (int mt = 0; mt < 4; ++mt)
#pragma unroll
        for (int nt = 0; nt < 4; ++nt)
            acc[mt][nt] = (floatx4){0.f, 0.f, 0.f, 0.f};

#pragma unroll 1
    for (int kc = 0; kc < 4; ++kc) {
#pragma unroll
        for (int it = 0; it < 2; ++it) {
            int i = tid + it * 256;
            int row = i >> 3, seg = i & 7;
            *(uint4*)(sA + row * 72 + seg * 8) =
                *(const uint4*)(gbf + (rowbase + row) * DD + kc * 64 + seg * 8);
        }
#pragma unroll
        for (int it = 0; it < 8; ++it) {
            int i = tid + it * 256;
            int n = i >> 3, seg = i & 7;
            *(uint4*)(sB + n * 72 + seg * 8) =
                *(const uint4*)(w1t + n * DD + kc * 64 + seg * 8);
        }
        __syncthreads();
#pragma unroll
        for (int ks = 0; ks < 2; ++ks) {
            short8 af[4], bfr[4];
#pragma unroll
            for (int mt = 0; mt < 4; ++mt)
                af[mt] = *(const short8*)(sA + (mt * 16 + cn) * 72 + ks * 32 + q * 8);
#pragma unroll
            for (int nt = 0; nt < 4; ++nt)
                bfr[nt] = *(const short8*)(sB + (n0 + nt * 16 + cn) * 72 + ks * 32 + q * 8);
#pragma unroll
            for (int mt = 0; mt < 4; ++mt)
#pragma unroll
                for (int nt = 0; nt < 4; ++nt)
                    acc[mt][nt] = __builtin_amdgcn_mfma_f32_16x16x32_bf16(
                        af[mt], bfr[nt], acc[mt][nt], 0, 0, 0);
        }
        __syncthreads();
    }

    ushort (*oS)[DD] = (ushort(*)[DD])sB;
#pragma unroll
    for (int mt = 0; mt < 4; ++mt)
#pragma unroll
        for (int nt = 0; nt < 4; ++nt)
#pragma unroll
            for (int r = 0; r < 4; ++r)
                oS[mt * 16 + q * 4 + r][n0 + nt * 16 + cn] = f2bf(acc[mt][nt][r]);
    __syncthreads();
#pragma unroll
    for (int it = 0; it < 8; ++it) {
        int i = tid + it * 256;
        int row = i >> 5, seg = i & 31;
        *(uint4*)(G + (rowbase + row) * DD + seg * 8) = *(const uint4*)(&oS[row][seg * 8]);
    }
}

__device__ __forceinline__ float pw(float z, float invv) {
    return hw_exp2(invv * hw_log2(z));   // z=0 -> exp2(-inf)=0, correct limit
}

// K4 (fused): stage G rows -> LDS (wide loads), partial scores, bisect on wave0
// while waves 1-3 stage gbf rows, then weighted sum + selu + L2 norm.
__global__ __launch_bounds__(256) void k_fused_entmax(
    const int* __restrict__ items, const ushort* __restrict__ G,
    const ushort* __restrict__ gbf, const float* __restrict__ t2,
    const float* __restrict__ alpha, const float* __restrict__ at_w0,
    float* __restrict__ out)
{
    __shared__ int s_it[64];
    __shared__ __align__(16) ushort sG[LL * DD];   // 25600 B
    __shared__ __align__(16) ushort sH[LL * DD];   // 25600 B
    __shared__ float sred[LL][4];
    __shared__ float attn_s[LL];
    __shared__ float red[4];
    int b = blockIdx.x;
    int tid = threadIdx.x;
    int lane = tid & 63, wv = tid >> 6;

    if (tid < LL) s_it[tid] = items[b * LL + tid];
    __syncthreads();

    // stage G rows: 50 rows x 32 uint4
    for (int i = tid; i < LL * 32; i += 256) {
        int row = i >> 5, seg = i & 31;
        *(uint4*)(sG + row * DD + seg * 8) =
            *(const uint4*)(G + (size_t)s_it[row] * DD + seg * 8);
    }
    __syncthreads();

    // phase 1: per-wave partial scores over this wave's 64 d's
    float t2v = t2[b * DD + tid];
    float w0v = at_w0[tid];
#pragma unroll
    for (int l = 0; l < LL; ++l) {
        float g = bf2f(sG[l * DD + tid]);
        float p = fmaxf(g + t2v, 0.f) * w0v;
        p = wave_sum64(p);
        if (lane == 0) sred[l][wv] = p;
    }
    __syncthreads();

    // phase 2: wave 0 bisects; waves 1-3 stage gbf rows for phase 3
    if (wv == 0) {
        int l = lane;
        float x = (l < LL) ? (sred[l][0] + sred[l][1] + sred[l][2] + sred[l][3])
                           : -__builtin_inff();
        float a = alpha[b];
        float am1 = a - 1.f;
        float invv = 1.f / am1;
        float Xa = x * am1;

        float mx = wave_max64(Xa);
        float tau_lo = mx - 1.f;
        float tau_hi = mx - hw_exp2(am1 * hw_log2(1.f / (float)LL));

        float f_lo = wave_sum64(pw(fmaxf(Xa - tau_lo, 0.f), invv)) - 1.f;

        float dm = tau_hi - tau_lo;
        float tau_m = tau_lo;
#pragma unroll 1
        for (int it = 0; it < NITER; ++it) {
            dm *= 0.5f;
            tau_m = tau_lo + dm;
            float f_m = wave_sum64(pw(fmaxf(Xa - tau_m, 0.f), invv)) - 1.f;
            if (f_m * f_lo >= 0.f) tau_lo = tau_m;
        }
        float pm = pw(fmaxf(Xa - tau_m, 0.f), invv);
        float s = wave_sum64(pm);
        if (l < LL) attn_s[l] = pm / s;
    } else {
        int idx = tid - 64;
        for (int i = idx; i < LL * 32; i += 192) {
            int row = i >> 5, seg = i & 31;
            *(uint4*)(sH + row * DD + seg * 8) =
                *(const uint4*)(gbf + (size_t)s_it[row] * DD + seg * 8);
        }
    }
    __syncthreads();

    // phase 3: weighted sum + selu + L2 norm
    float c = 0.f;
#pragma unroll
    for (int l = 0; l < LL; ++l)
        c += attn_s[l] * bf2f(sH[l * DD + tid]);

    const float SC = 1.0507009873554805f;
    const float AL = 1.6732632423543772f;
    c = SC * (c > 0.f ? c : AL * expm1f(c));

    float ss = wave_sum64(c * c);
    if (lane == 0) red[wv] = ss;
    __syncthreads();
    float tot = red[0] + red[1] + red[2] + red[3];
    out[b * DD + tid] = c / sqrtf(tot);
}

extern "C" void kernel_launch(void* const* d_in, const int* in_sizes, int n_in,
                              void* d_out, int out_size, void* d_ws, size_t ws_size,
                              hipStream_t stream) {
    const int*   items     = (const int*)  d_in[0];
    const float* tgt       = (const float*)d_in[3];
    const float* item_emb  = (const float*)d_in[4];
    const int*   adj_cols  = (const int*)  d_in[6];
    const float* adj_vals  = (const float*)d_in[7];
    const float* wf_w      = (const float*)d_in[8];
    const float* wf_b      = (const float*)d_in[9];
    const float* alphaw_w  = (const float*)d_in[10];
    const float* alphaw_b  = (const float*)d_in[11];
    const float* at_w0     = (const float*)d_in[12];
    const float* at_w1     = (const float*)d_in[13];
    const float* at_w2     = (const float*)d_in[14];
    const float* at_bias   = (const float*)d_in[15];

    const size_t SZ_TAB = (size_t)NN * DD * sizeof(ushort);      // 20.48 MB
    char* ws = (char*)d_ws;
    ushort* gbf = (ushort*)ws;   ws += SZ_TAB;                   // conv output (bf16)
    ushort* Gbf = (ushort*)ws;   ws += SZ_TAB;                   // gbf @ W1 (bf16)
    ushort* ebf = (ushort*)ws;   ws += SZ_TAB;                   // bf16 emb table
    ushort* w1t = (ushort*)ws;   ws += (size_t)DD * DD * sizeof(ushort);
    float* Wc    = (float*)ws;   ws += (size_t)TWO_D * DD * sizeof(float);
    float* bcv   = (float*)ws;   ws += (size_t)DD * sizeof(float);
    float* vv    = (float*)ws;   ws += (size_t)TWO_D * sizeof(float);
    float* c0v   = (float*)ws;   ws += 16 * sizeof(float);
    float* t2    = (float*)ws;   ws += (size_t)BB * DD * sizeof(float);
    float* alpha = (float*)ws;   ws += ((size_t)BB + 32) * sizeof(float);
    float* out   = (float*)d_out;

    k_emb_bf16<<<NN * DD / (256 * 4), 256, 0, stream>>>(item_emb, ebf);
    k_prep_w1<<<DD / 4, 256, 0, stream>>>(at_w1, w1t);
    k_wprep<<<TWO_D, 256, 0, stream>>>(wf_w, wf_b, at_w2, at_bias,
                                       alphaw_w, alphaw_b, Wc, vv, bcv, c0v);
    k_t2a<<<(BB / 4) * 4, 256, 0, stream>>>(tgt, Wc, bcv, vv, c0v, t2, alpha);
    k_conv_all_bf16<<<NN / 4, 256, 0, stream>>>(ebf, adj_cols, adj_vals, gbf);
    k_gw1<<<NN / 64, 256, 0, stream>>>(gbf, w1t, Gbf);
    k_fused_entmax<<<BB, 256, 0, stream>>>(items, Gbf, gbf, t2, alpha, at_w0, out);
}

// Round 7
// 239.405 us; speedup vs baseline: 1.1554x; 1.1554x over previous
//
#include <hip/hip_runtime.h>
#include <hip/hip_bf16.h>
#include <math.h>

#define BB 1024     // batch
#define LL 50       // sequence length
#define DD 256      // embedding dim
#define TWO_D 512
#define NN 40000    // nodes
#define DEG 12      // neighbors per node (adj_rows = repeat(arange(N), DEG))
#define NITER 50    // entmax bisect iterations

typedef __attribute__((ext_vector_type(8))) short short8;
typedef __attribute__((ext_vector_type(4))) float floatx4;

__device__ __forceinline__ float wave_sum64(float v) {
#pragma unroll
    for (int off = 32; off > 0; off >>= 1) v += __shfl_xor(v, off, 64);
    return v;
}
__device__ __forceinline__ float wave_max64(float v) {
#pragma unroll
    for (int off = 32; off > 0; off >>= 1) v = fmaxf(v, __shfl_xor(v, off, 64));
    return v;
}
__device__ __forceinline__ float bf2f(ushort u) {
    union { unsigned int i; float f; } c; c.i = ((unsigned int)u) << 16; return c.f;
}
__device__ __forceinline__ ushort f2bf(float f) {
    __hip_bfloat16 h = __float2bfloat16(f);
    return *(ushort*)&h;
}
__device__ __forceinline__ float hw_exp2(float x) { return __builtin_amdgcn_exp2f(x); }
__device__ __forceinline__ float hw_log2(float x) { return __builtin_amdgcn_logf(x); }

// K0: ebf = bf16(item_emb)
__global__ __launch_bounds__(256) void k_emb_bf16(
    const float* __restrict__ emb, ushort* __restrict__ ebf)
{
    int i = (blockIdx.x * 256 + threadIdx.x) * 4;
    float4 v = *(const float4*)(emb + i);
    ushort4 o;
    o.x = f2bf(v.x); o.y = f2bf(v.y); o.z = f2bf(v.z); o.w = f2bf(v.w);
    *(ushort4*)(ebf + i) = o;
}

// K1: per-node conv, one wave per node; 12 neighbor rows as in-flight loads.
__global__ __launch_bounds__(256) void k_conv_all_bf16(
    const ushort* __restrict__ ebf, const int* __restrict__ adj_cols,
    const float* __restrict__ adj_vals, ushort* __restrict__ gbf)
{
    int wv = threadIdx.x >> 6, lane = threadIdx.x & 63;
    int n = blockIdx.x * 4 + wv;
    int colv = 0; float valv = 0.f;
    if (lane < DEG) { colv = adj_cols[n * DEG + lane]; valv = adj_vals[n * DEG + lane]; }
    int cols[DEG]; float vals[DEG];
#pragma unroll
    for (int k = 0; k < DEG; ++k) {
        cols[k] = __shfl(colv, k, 64);
        vals[k] = __shfl(valv, k, 64);
    }
    ushort4 s = *(const ushort4*)(ebf + (size_t)n * DD + lane * 4);
    ushort4 e[DEG];
#pragma unroll
    for (int k = 0; k < DEG; ++k)
        e[k] = *(const ushort4*)(ebf + (size_t)cols[k] * DD + lane * 4);
    float a0 = bf2f(s.x), a1 = bf2f(s.y), a2 = bf2f(s.z), a3 = bf2f(s.w);
#pragma unroll
    for (int k = 0; k < DEG; ++k) {
        float v = vals[k];
        a0 += v * bf2f(e[k].x); a1 += v * bf2f(e[k].y);
        a2 += v * bf2f(e[k].z); a3 += v * bf2f(e[k].w);
    }
    ushort4 o;
    o.x = f2bf(0.5f * a0); o.y = f2bf(0.5f * a1);
    o.z = f2bf(0.5f * a2); o.w = f2bf(0.5f * a3);
    *(ushort4*)(gbf + (size_t)n * DD + lane * 4) = o;
}

// Kw (512 blocks): combined weights + w1 transpose fold.
//  Wc[k][n] = sum_d wf_w[d][k]*at_w2[d][n]; v[k] = sum_d wf_w[d][k]*aw[d]
//  block 0: bc[n], c0.  blocks k<256: w1t[k][t] = bf16(at_w1[t][k]).
__global__ __launch_bounds__(256) void k_wprep(
    const float* __restrict__ wf_w, const float* __restrict__ wf_b,
    const float* __restrict__ at_w2, const float* __restrict__ at_bias,
    const float* __restrict__ aw, const float* __restrict__ ab,
    const float* __restrict__ at_w1,
    float* __restrict__ Wc, float* __restrict__ v,
    float* __restrict__ bc, float* __restrict__ c0,
    ushort* __restrict__ w1t)
{
    __shared__ float wred[4];
    int k = blockIdx.x;
    int tid = threadIdx.x;
    int lane = tid & 63, wv = tid >> 6;

    float acc = 0.f;
#pragma unroll 4
    for (int d = 0; d < DD; ++d)
        acc += wf_w[d * TWO_D + k] * at_w2[d * DD + tid];
    Wc[k * DD + tid] = acc;

    float s1 = wf_w[tid * TWO_D + k] * aw[tid];
    s1 = wave_sum64(s1);
    if (lane == 0) wred[wv] = s1;
    __syncthreads();
    if (tid == 0) v[k] = wred[0] + wred[1] + wred[2] + wred[3];

    if (k < DD) w1t[k * DD + tid] = f2bf(at_w1[tid * DD + k]);

    if (k == 0) {
        float acc2 = at_bias[tid];
#pragma unroll 4
        for (int d = 0; d < DD; ++d)
            acc2 += wf_b[d] * at_w2[d * DD + tid];
        bc[tid] = acc2;
        __syncthreads();
        float s2 = wf_b[tid] * aw[tid];
        s2 = wave_sum64(s2);
        if (lane == 0) wred[wv] = s2;
        __syncthreads();
        if (tid == 0) c0[0] = wred[0] + wred[1] + wred[2] + wred[3] + ab[0];
    }
}

// Kt: t2[b,n] = tgt[b,:] @ Wc[:,n] + bc[n];  ntile==0 blocks also emit alpha.
__global__ __launch_bounds__(256) void k_t2a(
    const float* __restrict__ tgt, const float* __restrict__ Wc,
    const float* __restrict__ bc, const float* __restrict__ v,
    const float* __restrict__ c0, float* __restrict__ t2,
    float* __restrict__ alpha)
{
    __shared__ float x_s[4 * TWO_D];
    int btile = blockIdx.x >> 2, ntile = blockIdx.x & 3;
    int b0 = btile * 4, n0 = ntile * 64;
    int tid = threadIdx.x;
    int j = tid >> 6, lane = tid & 63;
    for (int i = tid; i < 4 * TWO_D; i += 256) x_s[i] = tgt[b0 * TWO_D + i];
    __syncthreads();

    float acc = bc[n0 + lane];
    const float* xr = x_s + j * TWO_D;
#pragma unroll 8
    for (int k = 0; k < TWO_D; ++k)
        acc += xr[k] * Wc[k * DD + n0 + lane];
    t2[(b0 + j) * DD + n0 + lane] = acc;

    if (ntile == 0) {
        float s = 0.f;
#pragma unroll
        for (int i = 0; i < 8; ++i) s += xr[lane + 64 * i] * v[lane + 64 * i];
        s = wave_sum64(s);
        if (lane == 0) {
            float a = 1.f + 1.f / (1.f + expf(-(s + c0[0])));
            if (a == 1.f) a = 1.00001f;
            alpha[b0 + j] = a;
        }
    }
}

// K3 (MFMA): scores[row] = sum_n relu( (H@W1)[row,n] + t2[b,n] ) * w0[n]
// A rows gathered on the fly: H[row] = gbf[items[row]].  (R4-proven)
__global__ __launch_bounds__(256) void k_scores_mfma(
    const int* __restrict__ items, const ushort* __restrict__ gbf,
    const ushort* __restrict__ w1t, const float* __restrict__ t2,
    const float* __restrict__ at_w0, float* __restrict__ scores)
{
    __shared__ __align__(16) ushort sA[64 * 72];
    __shared__ __align__(16) ushort sB[256 * 72];
    __shared__ float sred[64][4];
    __shared__ int s_items[64];
    int tid = threadIdx.x;
    int blk = blockIdx.x;
    int lane = tid & 63, wv = tid >> 6;
    int cn = lane & 15, q = lane >> 4;
    int n0 = wv * 64;

    if (tid < 64) s_items[tid] = items[blk * 64 + tid];
    __syncthreads();

    floatx4 acc[4][4];
#pragma unroll
    for (int mt = 0; mt < 4; ++mt)
#pragma unroll
        for (int nt = 0; nt < 4; ++nt)
            acc[mt][nt] = (floatx4){0.f, 0.f, 0.f, 0.f};

#pragma unroll 1
    for (int kc = 0; kc < 4; ++kc) {
#pragma unroll
        for (int it = 0; it < 2; ++it) {
            int i = tid + it * 256;
            int row = i >> 3, seg = i & 7;
            *(uint4*)(sA + row * 72 + seg * 8) =
                *(const uint4*)(gbf + (size_t)s_items[row] * DD + kc * 64 + seg * 8);
        }
#pragma unroll
        for (int it = 0; it < 8; ++it) {
            int i = tid + it * 256;
            int n = i >> 3, seg = i & 7;
            *(uint4*)(sB + n * 72 + seg * 8) =
                *(const uint4*)(w1t + n * DD + kc * 64 + seg * 8);
        }
        __syncthreads();
#pragma unroll
        for (int ks = 0; ks < 2; ++ks) {
            short8 af[4], bfr[4];
#pragma unroll
            for (int mt = 0; mt < 4; ++mt)
                af[mt] = *(const short8*)(sA + (mt * 16 + cn) * 72 + ks * 32 + q * 8);
#pragma unroll
            for (int nt = 0; nt < 4; ++nt)
                bfr[nt] = *(const short8*)(sB + (n0 + nt * 16 + cn) * 72 + ks * 32 + q * 8);
#pragma unroll
            for (int mt = 0; mt < 4; ++mt)
#pragma unroll
                for (int nt = 0; nt < 4; ++nt)
                    acc[mt][nt] = __builtin_amdgcn_mfma_f32_16x16x32_bf16(
                        af[mt], bfr[nt], acc[mt][nt], 0, 0, 0);
        }
        __syncthreads();
    }

    float w0v[4];
#pragma unroll
    for (int nt = 0; nt < 4; ++nt) w0v[nt] = at_w0[n0 + nt * 16 + cn];
#pragma unroll
    for (int mt = 0; mt < 4; ++mt) {
#pragma unroll
        for (int r = 0; r < 4; ++r) {
            int row_in = q * 4 + r;
            int row_g = blk * 64 + mt * 16 + row_in;
            int b = row_g / LL;
            const float* t2b = t2 + b * DD;
            float p = 0.f;
#pragma unroll
            for (int nt = 0; nt < 4; ++nt) {
                int col = n0 + nt * 16 + cn;
                float v = acc[mt][nt][r] + t2b[col];
                p += fmaxf(v, 0.f) * w0v[nt];
            }
            p += __shfl_xor(p, 1, 64);
            p += __shfl_xor(p, 2, 64);
            p += __shfl_xor(p, 4, 64);
            p += __shfl_xor(p, 8, 64);
            if (cn == 0) sred[mt * 16 + row_in][wv] = p;
        }
    }
    __syncthreads();
    if (tid < 64)
        scores[blk * 64 + tid] = sred[tid][0] + sred[tid][1] + sred[tid][2] + sred[tid][3];
}

__device__ __forceinline__ float pw(float z, float invv) {
    return hw_exp2(invv * hw_log2(z));   // z=0 -> exp2(-inf)=0, correct limit
}

// K4: wave 0 bisects (scores from global); waves 1-3 stage gbf rows to LDS;
// then weighted sum + selu + L2 norm.
__global__ __launch_bounds__(256) void k_entmax_out(
    const float* __restrict__ scores, const float* __restrict__ alpha,
    const int* __restrict__ items, const ushort* __restrict__ gbf,
    float* __restrict__ out)
{
    __shared__ int s_it[64];
    __shared__ __align__(16) ushort sH[LL * DD];   // 25600 B
    __shared__ float attn_s[LL];
    __shared__ float red[4];
    int b = blockIdx.x;
    int tid = threadIdx.x;
    int lane = tid & 63, wv = tid >> 6;

    if (tid < LL) s_it[tid] = items[b * LL + tid];
    __syncthreads();

    if (wv == 0) {
        int l = lane;
        float x = (l < LL) ? scores[b * LL + l] : -__builtin_inff();
        float a = alpha[b];
        float am1 = a - 1.f;
        float invv = 1.f / am1;
        float Xa = x * am1;

        float mx = wave_max64(Xa);
        float tau_lo = mx - 1.f;
        float tau_hi = mx - hw_exp2(am1 * hw_log2(1.f / (float)LL));

        float f_lo = wave_sum64(pw(fmaxf(Xa - tau_lo, 0.f), invv)) - 1.f;

        float dm = tau_hi - tau_lo;
        float tau_m = tau_lo;
#pragma unroll 1
        for (int it = 0; it < NITER; ++it) {
            dm *= 0.5f;
            tau_m = tau_lo + dm;
            float f_m = wave_sum64(pw(fmaxf(Xa - tau_m, 0.f), invv)) - 1.f;
            if (f_m * f_lo >= 0.f) tau_lo = tau_m;
        }
        float pm = pw(fmaxf(Xa - tau_m, 0.f), invv);
        float s = wave_sum64(pm);
        if (l < LL) attn_s[l] = pm / s;
    } else {
        int idx = tid - 64;
        for (int i = idx; i < LL * 32; i += 192) {
            int row = i >> 5, seg = i & 31;
            *(uint4*)(sH + row * DD + seg * 8) =
                *(const uint4*)(gbf + (size_t)s_it[row] * DD + seg * 8);
        }
    }
    __syncthreads();

    float c = 0.f;
#pragma unroll
    for (int l = 0; l < LL; ++l)
        c += attn_s[l] * bf2f(sH[l * DD + tid]);

    const float SC = 1.0507009873554805f;
    const float AL = 1.6732632423543772f;
    c = SC * (c > 0.f ? c : AL * expm1f(c));

    float ss = wave_sum64(c * c);
    if (lane == 0) red[wv] = ss;
    __syncthreads();
    float tot = red[0] + red[1] + red[2] + red[3];
    out[b * DD + tid] = c / sqrtf(tot);
}

extern "C" void kernel_launch(void* const* d_in, const int* in_sizes, int n_in,
                              void* d_out, int out_size, void* d_ws, size_t ws_size,
                              hipStream_t stream) {
    const int*   items     = (const int*)  d_in[0];
    const float* tgt       = (const float*)d_in[3];
    const float* item_emb  = (const float*)d_in[4];
    const int*   adj_cols  = (const int*)  d_in[6];
    const float* adj_vals  = (const float*)d_in[7];
    const float* wf_w      = (const float*)d_in[8];
    const float* wf_b      = (const float*)d_in[9];
    const float* alphaw_w  = (const float*)d_in[10];
    const float* alphaw_b  = (const float*)d_in[11];
    const float* at_w0     = (const float*)d_in[12];
    const float* at_w1     = (const float*)d_in[13];
    const float* at_w2     = (const float*)d_in[14];
    const float* at_bias   = (const float*)d_in[15];

    const size_t SZ_TAB = (size_t)NN * DD * sizeof(ushort);      // 20.48 MB
    char* ws = (char*)d_ws;
    ushort* gbf = (ushort*)ws;   ws += SZ_TAB;
    ushort* ebf = (ushort*)ws;   ws += SZ_TAB;
    ushort* w1t = (ushort*)ws;   ws += (size_t)DD * DD * sizeof(ushort);
    float* Wc    = (float*)ws;   ws += (size_t)TWO_D * DD * sizeof(float);
    float* bcv   = (float*)ws;   ws += (size_t)DD * sizeof(float);
    float* vv    = (float*)ws;   ws += (size_t)TWO_D * sizeof(float);
    float* c0v   = (float*)ws;   ws += 16 * sizeof(float);
    float* t2    = (float*)ws;   ws += (size_t)BB * DD * sizeof(float);
    float* alpha = (float*)ws;   ws += ((size_t)BB + 32) * sizeof(float);
    float* scores = (float*)ws;  ws += (size_t)BB * LL * sizeof(float);
    float* out   = (float*)d_out;

    k_emb_bf16<<<NN * DD / (256 * 4), 256, 0, stream>>>(item_emb, ebf);
    k_wprep<<<TWO_D, 256, 0, stream>>>(wf_w, wf_b, at_w2, at_bias,
                                       alphaw_w, alphaw_b, at_w1,
                                       Wc, vv, bcv, c0v, w1t);
    k_t2a<<<(BB / 4) * 4, 256, 0, stream>>>(tgt, Wc, bcv, vv, c0v, t2, alpha);
    k_conv_all_bf16<<<NN / 4, 256, 0, stream>>>(ebf, adj_cols, adj_vals, gbf);
    k_scores_mfma<<<(BB * LL) / 64, 256, 0, stream>>>(items, gbf, w1t, t2, at_w0, scores);
    k_entmax_out<<<BB, 256, 0, stream>>>(scores, alpha, items, gbf, out);
}